// Round 5
// baseline (133.653 us; speedup 1.0000x reference)
//
#include <hip/hip_runtime.h>
#include <stdint.h>

typedef __attribute__((ext_vector_type(8))) __bf16 bf16x8;
typedef __attribute__((ext_vector_type(4))) float f32x4;

// Selected upper-tri circular-adjacency pairs (r,c), row-major triu order. K=64.
__device__ const unsigned char dR[64] = {
  0,0,0,0,0,0,0,
  1,1,1,1,1,1,
  2,2,2,2,2,
  3,3,3,3,
  4,4,4,4,
  5,5,5,5,
  6,6,6,6,
  7,7,7,7,
  8,8,8,8,
  9,9,9,9,
  10,10,10,10,
  11,11,11,11,
  12,12,12,12,
  13,13,13,
  14,14,
  15};
__device__ const unsigned char dC[64] = {
  0,1,2,3,13,14,15,
  1,2,3,4,14,15,
  2,3,4,5,15,
  3,4,5,6,
  4,5,6,7,
  5,6,7,8,
  6,7,8,9,
  7,8,9,10,
  8,9,10,11,
  9,10,11,12,
  10,11,12,13,
  11,12,13,14,
  12,13,14,15,
  13,14,15,
  14,15,
  15};

__device__ __forceinline__ unsigned short f2bf(float x){
  unsigned u = __builtin_bit_cast(unsigned, x);
  return (unsigned short)((u + 0x7FFFu + ((u >> 16) & 1u)) >> 16);
}

// fp32 -> bf16 weight conversion into workspace (2.62 MB total)
__global__ void conv_w_kernel(const float* __restrict__ w1, const float* __restrict__ w2,
                              unsigned short* __restrict__ o1, unsigned short* __restrict__ o2){
  int i = blockIdx.x * 256 + threadIdx.x;
  if (i < 262144){
    float4 v = ((const float4*)w1)[i];
    ushort4 pk; pk.x=f2bf(v.x); pk.y=f2bf(v.y); pk.z=f2bf(v.z); pk.w=f2bf(v.w);
    ((ushort4*)o1)[i] = pk;
  } else {
    int j = i - 262144;
    if (j < 65536){
      float4 v = ((const float4*)w2)[j];
      ushort4 pk; pk.x=f2bf(v.x); pk.y=f2bf(v.y); pk.z=f2bf(v.z); pk.w=f2bf(v.w);
      ((ushort4*)o2)[j] = pk;
    }
  }
}

// LDS: phase 1: gather A-tile dbuf 2 x 6144 B @ 0 / 6144.
//      phase 2: A1 [96 rows][512 h] bf16 XOR-swizzled @ [0, 98304) (aliases, post-barrier)
#define LB0 0
#define LB1 6144

// issue 6 gather loads (2-step flight) into static slot SLOT
#define GISS(SLOT, FV, PAR) do{ const float* xf_ = xb + ((long)(FV) << 16);               \
  _Pragma("unroll") for (int o_ = 0; o_ < 3; ++o_)                                        \
  _Pragma("unroll") for (int e_ = 0; e_ < 2; ++e_)                                        \
    g##SLOT[o_][e_] = xf_[poff[PAR][o_][e_]]; }while(0)

// direct-L2 W1 fragment loads (register ping-pong, wave-private)
#define WLOAD(DST, BYOFF) do{ _Pragma("unroll") for (int cn_ = 0; cn_ < 4; ++cn_)         \
  DST[cn_] = *(const bf16x8*)(w1c + wfo[cn_] + (BYOFF)); }while(0)

// cvt slot -> ds_write A-tile into buffer BUFOFF
#define CVTWR(SLOT, BUFOFF) do{ _Pragma("unroll") for (int o_ = 0; o_ < 3; ++o_){         \
  unsigned pv_ = (unsigned)f2bf(g##SLOT[o_][0]) | ((unsigned)f2bf(g##SLOT[o_][1]) << 16); \
  *(unsigned*)(lds + (BUFOFF) + awr + (o_ << 9)) = pv_; } }while(0)

// 6 A-frag ds_reads + 24 MFMA
#define MM(BUFOFF, BW) do{ bf16x8 af_[6];                                                 \
  _Pragma("unroll") for (int fm_ = 0; fm_ < 6; ++fm_)                                     \
    af_[fm_] = *(const bf16x8*)(lds + (BUFOFF) + ard + fm_*256);                          \
  __builtin_amdgcn_s_setprio(1);                                                          \
  _Pragma("unroll") for (int cn_ = 0; cn_ < 4; ++cn_)                                     \
  _Pragma("unroll") for (int fm_ = 0; fm_ < 6; ++fm_)                                     \
    acc[fm_][cn_] = __builtin_amdgcn_mfma_f32_16x16x32_bf16(af_[fm_], BW[cn_], acc[fm_][cn_], 0, 0, 0); \
  __builtin_amdgcn_s_setprio(0); }while(0)

// LDS-only barrier: no vmcnt drain (all global loads are register loads, compiler-tracked)
#define BAR() do{ asm volatile("s_waitcnt lgkmcnt(0)" ::: "memory");                      \
  __builtin_amdgcn_s_barrier(); asm volatile("" ::: "memory"); }while(0)

#define A2SUB(ss, cc) do{                                                                 \
  bf16x8 a2[6];                                                                           \
  _Pragma("unroll") for (int fm = 0; fm < 6; ++fm){                                       \
    int byt = (((fm << 4) + lr) << 10) + ((ss) << 6) + (q << 4);                          \
    byt ^= (lr & 7) << 4;                                                                 \
    a2[fm] = *(const bf16x8*)(lds + byt);                                                 \
  }                                                                                       \
  _Pragma("unroll") for (int cn = 0; cn < 4; ++cn)                                        \
    _Pragma("unroll") for (int fm = 0; fm < 6; ++fm)                                      \
      acc2[fm][cn] = __builtin_amdgcn_mfma_f32_16x16x32_bf16(a2[fm], cc[cn], acc2[fm][cn], 0, 0, 0); \
}while(0)

// Block = (b, 32-t tile): 256 blocks, 512 threads (8 waves). Each wave: [96m x 64n].
__global__ __launch_bounds__(512, 2)
void fused_kernel(const float* __restrict__ x,
                  const float* __restrict__ b1v,
                  const float* __restrict__ b2v,
                  const unsigned short* __restrict__ w1b,
                  const unsigned short* __restrict__ w2b,
                  float* __restrict__ out)
{
  __shared__ char lds[98304];
  const int bid = blockIdx.x;
  const int b   = bid >> 3;
  const int t0  = (bid & 7) << 5;

  const int tid  = threadIdx.x;
  const int w    = tid >> 6;
  const int lane = tid & 63;
  const int q    = lane >> 4;
  const int lr   = lane & 15;
  const int u    = tid >> 5;          // [0,16): k-pair index for gather
  const int tt   = tid & 31;          // t within tile for gather

  // gather source offsets: k = par*32 + 2u + e
  int poff[2][3][2];
#pragma unroll
  for (int par = 0; par < 2; ++par)
#pragma unroll
    for (int e = 0; e < 2; ++e){
      const int k = par * 32 + 2 * u + e;
      const int r = dR[k], c = dC[k];
#pragma unroll
      for (int o = 0; o < 3; ++o){
        const int v = o - 1;                         // mean over o is order-free
        poff[par][o][e] = ((((r - v) & 15) << 4) | ((c - v) & 15)) << 8;
      }
    }
  const float* xb = x + (((long)b << 21) + t0 + tt);

  // A-tile ds_write base: layout [kb4][row96][16B], kb stride 1536
  const int awr = ((u >> 2) * 1536) + (tt << 4) + ((u & 3) << 2);   // + o*512
  // A-frag read base (16 consecutive rows per lane-quarter)
  const int ard = q * 1536 + (lr << 4);                              // + fm*256
  // W1 fragment offsets (direct global; [col][k] row-major, pitch 4096 B)
  const char* w1c = (const char*)w1b;
  int wfo[4];
  float b1c[4];
#pragma unroll
  for (int cn = 0; cn < 4; ++cn){
    const int col = (w << 6) + (cn << 4) + lr;
    wfo[cn] = col * 4096 + (q << 4);
    b1c[cn] = b1v[col];
  }

  f32x4 acc[6][4];
#pragma unroll
  for (int fm = 0; fm < 6; ++fm)
#pragma unroll
    for (int cn = 0; cn < 4; ++cn)
      acc[fm][cn] = f32x4{0.f, 0.f, 0.f, 0.f};

  float g0[3][2], g1[3][2], g2[3][2], g3[3][2];
  bf16x8 bwA[4], bwB[4];

  // ---------------- prologue ----------------
  // in-flight: slot2 = tile 1 (f0,par1), slot3 = tile 2 (f1,par0); W frags step 0
  GISS(2, 0, 1);
  GISS(3, 1, 0);
  WLOAD(bwA, 0);
  {
    // tile 0 (f0,par0): load + cvt + write buf0 immediately
    float gp[3][2];
#pragma unroll
    for (int o_ = 0; o_ < 3; ++o_)
#pragma unroll
      for (int e_ = 0; e_ < 2; ++e_)
        gp[o_][e_] = xb[poff[0][o_][e_]];
#pragma unroll
    for (int o_ = 0; o_ < 3; ++o_){
      unsigned pv_ = (unsigned)f2bf(gp[o_][0]) | ((unsigned)f2bf(gp[o_][1]) << 16);
      *(unsigned*)(lds + LB0 + awr + (o_ << 9)) = pv_;
    }
  }
  BAR();

  // ---------------- phase 1: 64 K-steps (4x unrolled), LDS-only barriers ----------
#pragma unroll 1
  for (int it = 0; it < 16; ++it){
    const int wb = it << 8;           // W byte offset base = N*64 with N=4it
    const int f2i = it << 1;
    const int last = (it == 15);
    // j=0 (N=4it): read buf0/bwA; cvt slot2 -> buf1; issue slot0 <- tile N+3
    GISS(0, f2i + 1, 1);
    __builtin_amdgcn_sched_barrier(0);
    WLOAD(bwB, wb + 64);
    MM(LB0, bwA);
    CVTWR(2, LB1);
    BAR();
    // j=1: read buf1/bwB; cvt slot3 -> buf0; issue slot1 <- tile N+3
    if (!last) GISS(1, f2i + 2, 0);
    __builtin_amdgcn_sched_barrier(0);
    WLOAD(bwA, wb + 128);
    MM(LB1, bwB);
    CVTWR(3, LB0);
    BAR();
    // j=2: read buf0/bwA; cvt slot0 -> buf1; issue slot2
    if (!last) GISS(2, f2i + 2, 1);
    __builtin_amdgcn_sched_barrier(0);
    WLOAD(bwB, wb + 192);
    MM(LB0, bwA);
    CVTWR(0, LB1);
    BAR();
    // j=3: read buf1/bwB; cvt slot1 -> buf0; issue slot3
    if (!last) GISS(3, f2i + 3, 0);
    __builtin_amdgcn_sched_barrier(0);
    if (!last) WLOAD(bwA, wb + 256);
    MM(LB1, bwB);
    if (!last) CVTWR(1, LB0);
    BAR();
  }

  // ---------------- epilogue 1: bias + leaky -> A1 bf16 (XOR-swizzled) --------
#pragma unroll
  for (int cn = 0; cn < 4; ++cn){
    const int h  = (w << 6) + (cn << 4) + lr;
#pragma unroll
    for (int fm = 0; fm < 6; ++fm)
#pragma unroll
      for (int r = 0; r < 4; ++r){
        float vv = acc[fm][cn][r] + b1c[cn];
        vv = vv > 0.f ? vv : 0.01f * vv;
        const int row = (fm << 4) + (q << 2) + r;    // D row = 4*(lane>>4)+reg
        int byt = (row << 10) + (h << 1);
        byt ^= (row & 7) << 4;
        *(unsigned short*)(lds + byt) = f2bf(vv);
      }
  }
  BAR();

  // ---------------- phase 2: K=512 vs W2 (direct L2 frags), barrier-free ------
  int w2off[4];
  float b2c[4];
#pragma unroll
  for (int cn = 0; cn < 4; ++cn){
    const int col = (w << 6) + (cn << 4) + lr;
    w2off[cn] = col * 1024 + (q << 4);
    b2c[cn] = b2v[col];
  }
  const char* w2c = (const char*)w2b;
  f32x4 acc2[6][4];
#pragma unroll
  for (int fm = 0; fm < 6; ++fm)
#pragma unroll
    for (int cn = 0; cn < 4; ++cn)
      acc2[fm][cn] = f32x4{0.f, 0.f, 0.f, 0.f};

  bf16x8 c0[4], c1[4];
#pragma unroll
  for (int cn = 0; cn < 4; ++cn) c0[cn] = *(const bf16x8*)(w2c + w2off[cn]);

#pragma unroll 1
  for (int it2 = 0; it2 < 8; ++it2){
    const int s0 = it2 << 1;
#pragma unroll
    for (int cn = 0; cn < 4; ++cn) c1[cn] = *(const bf16x8*)(w2c + w2off[cn] + ((s0 + 1) << 6));
    A2SUB(s0, c0);
    if (it2 < 7){
#pragma unroll
      for (int cn = 0; cn < 4; ++cn) c0[cn] = *(const bf16x8*)(w2c + w2off[cn] + ((s0 + 2) << 6));
    }
    A2SUB(s0 + 1, c1);
  }

  // ---------------- epilogue 2: bias + leaky + mean(o) -> [B,H,T] -------------
#pragma unroll
  for (int cn = 0; cn < 4; ++cn){
    const int h  = (w << 6) + (cn << 4) + lr;
#pragma unroll
    for (int p = 0; p < 2; ++p){
      f32x4 ov;
#pragma unroll
      for (int r = 0; r < 4; ++r){
        float s = 0.f;
#pragma unroll
        for (int oo = 0; oo < 3; ++oo){
          float vv = acc2[oo * 2 + p][cn][r] + b2c[cn];
          vv = vv > 0.f ? vv : 0.01f * vv;
          s += vv;
        }
        ov[r] = s * (1.f / 3.f);
      }
      *(f32x4*)(out + (((long)b * 512 + h) << 8) + t0 + (p << 4) + (q << 2)) = ov;
    }
  }
}

extern "C" void kernel_launch(void* const* d_in, const int* in_sizes, int n_in,
                              void* d_out, int out_size, void* d_ws, size_t ws_size,
                              hipStream_t stream){
  const float* x  = (const float*)d_in[0];
  const float* w1 = (const float*)d_in[1];
  const float* b1 = (const float*)d_in[2];
  const float* w2 = (const float*)d_in[3];
  const float* b2 = (const float*)d_in[4];
  unsigned short* w1b = (unsigned short*)d_ws;            // 512*2048 bf16 = 2 MiB
  unsigned short* w2b = w1b + 512 * 2048;                 // 512*512  bf16 = 0.5 MiB
  conv_w_kernel<<<1280, 256, 0, stream>>>(w1, w2, w1b, w2b);
  fused_kernel<<<256, 512, 0, stream>>>(x, b1, b2, w1b, w2b, (float*)d_out);
}

// Round 6
// 100.558 us; speedup vs baseline: 1.3291x; 1.3291x over previous
//
#include <hip/hip_runtime.h>
#include <stdint.h>

typedef __attribute__((ext_vector_type(8))) __bf16 bf16x8;
typedef __attribute__((ext_vector_type(4))) float f32x4;

// Selected upper-tri circular-adjacency pairs (r,c), row-major triu order. K=64.
__device__ const unsigned char dR[64] = {
  0,0,0,0,0,0,0,
  1,1,1,1,1,1,
  2,2,2,2,2,
  3,3,3,3,
  4,4,4,4,
  5,5,5,5,
  6,6,6,6,
  7,7,7,7,
  8,8,8,8,
  9,9,9,9,
  10,10,10,10,
  11,11,11,11,
  12,12,12,12,
  13,13,13,
  14,14,
  15};
__device__ const unsigned char dC[64] = {
  0,1,2,3,13,14,15,
  1,2,3,4,14,15,
  2,3,4,5,15,
  3,4,5,6,
  4,5,6,7,
  5,6,7,8,
  6,7,8,9,
  7,8,9,10,
  8,9,10,11,
  9,10,11,12,
  10,11,12,13,
  11,12,13,14,
  12,13,14,15,
  13,14,15,
  14,15,
  15};

__device__ __forceinline__ unsigned short f2bf(float x){
  unsigned u = __builtin_bit_cast(unsigned, x);
  return (unsigned short)((u + 0x7FFFu + ((u >> 16) & 1u)) >> 16);
}

__device__ __forceinline__ void gl16(const void* g, void* l){
  __builtin_amdgcn_global_load_lds((const __attribute__((address_space(1))) unsigned int*)g,
                                   (__attribute__((address_space(3))) unsigned int*)l,
                                   16, 0, 0);
}

// fp32 -> bf16 weight conversion into workspace (2.62 MB total)
__global__ void conv_w_kernel(const float* __restrict__ w1, const float* __restrict__ w2,
                              unsigned short* __restrict__ o1, unsigned short* __restrict__ o2){
  int i = blockIdx.x * 256 + threadIdx.x;
  if (i < 262144){
    float4 v = ((const float4*)w1)[i];
    ushort4 pk; pk.x=f2bf(v.x); pk.y=f2bf(v.y); pk.z=f2bf(v.z); pk.w=f2bf(v.w);
    ((ushort4*)o1)[i] = pk;
  } else {
    int j = i - 262144;
    if (j < 65536){
      float4 v = ((const float4*)w2)[j];
      ushort4 pk; pk.x=f2bf(v.x); pk.y=f2bf(v.y); pk.z=f2bf(v.z); pk.w=f2bf(v.w);
      ((ushort4*)o2)[j] = pk;
    }
  }
}

// LDS: phase 1: W dbuf 2 x 32 KB @ 0 / 32768 (wave-private 4 KB regions),
//               gather A dbuf 2 x 6144 B @ 65536 / 71680.
//      phase 2: A1 [96 rows][512 h] bf16 XOR-swizzled @ [0, 98304) (aliases, post-barrier)
#define LW0 0
#define LW1 32768
#define LA0 65536
#define LA1 71680

// stage next W tile (wave-private cols) via global_load_lds, no barrier needed
#define WSTAGE(WBUF, BYOFF) do{ _Pragma("unroll") for (int i_ = 0; i_ < 4; ++i_)          \
  gl16((const char*)w1b + wso[i_] + (BYOFF), lds + (WBUF) + wdb[i_]); }while(0)

// issue 6 gather register loads (2-step flight) into static slot S (parity of tile)
#define GISS(S, FV) do{ const float* xf_ = xb + ((long)(FV) << 16);                       \
  _Pragma("unroll") for (int o_ = 0; o_ < 3; ++o_)                                        \
  _Pragma("unroll") for (int e_ = 0; e_ < 2; ++e_)                                        \
    g##S[o_][e_] = xf_[poff[S][o_][e_]]; }while(0)

// cvt slot -> ds_write A-tile into buffer BUFOFF (compiler auto-waits vmcnt for g regs)
#define CVTWR(S, BUFOFF) do{ _Pragma("unroll") for (int o_ = 0; o_ < 3; ++o_){            \
  unsigned pv_ = (unsigned)f2bf(g##S[o_][0]) | ((unsigned)f2bf(g##S[o_][1]) << 16);       \
  *(unsigned*)(lds + (BUFOFF) + awr + (o_ << 9)) = pv_; } }while(0)

// counted vmcnt: ensure the gl16 group from LAST step has landed (16 loads issued since)
#define VW(N) asm volatile("s_waitcnt vmcnt(" #N ")" ::: "memory")

// 6 A-frag + 4 W-frag ds_reads, 24 MFMA
#define MM(ABUF, WBUF) do{ bf16x8 af_[6], bw_[4];                                         \
  _Pragma("unroll") for (int fm_ = 0; fm_ < 6; ++fm_)                                     \
    af_[fm_] = *(const bf16x8*)(lds + (ABUF) + ard + fm_*256);                            \
  _Pragma("unroll") for (int cn_ = 0; cn_ < 4; ++cn_)                                     \
    bw_[cn_] = *(const bf16x8*)(lds + (WBUF) + wrd[cn_]);                                 \
  _Pragma("unroll") for (int cn_ = 0; cn_ < 4; ++cn_)                                     \
  _Pragma("unroll") for (int fm_ = 0; fm_ < 6; ++fm_)                                     \
    acc[fm_][cn_] = __builtin_amdgcn_mfma_f32_16x16x32_bf16(af_[fm_], bw_[cn_], acc[fm_][cn_], 0, 0, 0); \
}while(0)

// LDS-only barrier: lgkmcnt(0) (ds reads+writes done) + s_barrier. NO vmcnt drain.
#define BAR() do{ asm volatile("s_waitcnt lgkmcnt(0)" ::: "memory");                      \
  __builtin_amdgcn_s_barrier(); asm volatile("" ::: "memory"); }while(0)

#define A2SUB(ss, cc) do{                                                                 \
  bf16x8 a2[6];                                                                           \
  _Pragma("unroll") for (int fm = 0; fm < 6; ++fm){                                       \
    int byt = (((fm << 4) + lr) << 10) + ((ss) << 6) + (q << 4);                          \
    byt ^= (lr & 7) << 4;                                                                 \
    a2[fm] = *(const bf16x8*)(lds + byt);                                                 \
  }                                                                                       \
  _Pragma("unroll") for (int cn = 0; cn < 4; ++cn)                                        \
    _Pragma("unroll") for (int fm = 0; fm < 6; ++fm)                                      \
      acc2[fm][cn] = __builtin_amdgcn_mfma_f32_16x16x32_bf16(a2[fm], cc[cn], acc2[fm][cn], 0, 0, 0); \
}while(0)

// Block = (b, 32-t tile): 256 blocks, 512 threads (8 waves). Each wave: [96m x 64n].
__global__ __launch_bounds__(512, 2)
void fused_kernel(const float* __restrict__ x,
                  const float* __restrict__ b1v,
                  const float* __restrict__ b2v,
                  const unsigned short* __restrict__ w1b,
                  const unsigned short* __restrict__ w2b,
                  float* __restrict__ out)
{
  __shared__ char lds[98304];
  const int bid = blockIdx.x;
  const int b   = bid >> 3;
  const int t0  = (bid & 7) << 5;

  const int tid  = threadIdx.x;
  const int w    = tid >> 6;
  const int lane = tid & 63;
  const int q    = lane >> 4;
  const int lr   = lane & 15;
  const int u    = tid >> 5;          // [0,16): k-pair index for gather
  const int tt   = tid & 31;          // t within tile for gather

  // gather source offsets: k = par*32 + 2u + e
  int poff[2][3][2];
#pragma unroll
  for (int par = 0; par < 2; ++par)
#pragma unroll
    for (int e = 0; e < 2; ++e){
      const int k = par * 32 + 2 * u + e;
      const int r = dR[k], c = dC[k];
#pragma unroll
      for (int o = 0; o < 3; ++o){
        const int v = o - 1;                         // mean over o is order-free
        poff[par][o][e] = ((((r - v) & 15) << 4) | ((c - v) & 15)) << 8;
      }
    }
  const float* xb = x + (((long)b << 21) + t0 + tt);

  // A-tile ds_write base: layout [kb4][row96][16B], kb stride 1536
  const int awr = ((u >> 2) * 1536) + (tt << 4) + ((u & 3) << 2);   // + o*512
  // A-frag read base (16 consecutive rows per lane-quarter)
  const int ard = q * 1536 + (lr << 4);                              // + fm*256
  // W-frag read offsets ([col][k] pitch 64B, slot-swizzled)
  int wrd[4];
#pragma unroll
  for (int cn = 0; cn < 4; ++cn){
    const int col = (w << 6) + (cn << 4) + lr;
    wrd[cn] = col * 64 + ((q ^ ((col >> 1) & 3)) << 4);
  }
  // W stage: linear LDS dest (wave-uniform base), inverse-swizzled global source
  int wso[4], wdb[4];
#pragma unroll
  for (int i = 0; i < 4; ++i){
    const int colb = (w << 6) + (i << 4);
    const int col  = colb + (lane >> 2);
    wso[i] = col * 4096 + (((lane & 3) ^ ((col >> 1) & 3)) << 4);
    wdb[i] = colb * 64;
  }
  float b1c[4];
#pragma unroll
  for (int cn = 0; cn < 4; ++cn) b1c[cn] = b1v[(w << 6) + (cn << 4) + lr];

  f32x4 acc[6][4];
#pragma unroll
  for (int fm = 0; fm < 6; ++fm)
#pragma unroll
    for (int cn = 0; cn < 4; ++cn)
      acc[fm][cn] = f32x4{0.f, 0.f, 0.f, 0.f};

  float g0[3][2], g1[3][2];

  // ---------------- prologue ----------------
  {
    float gp[3][2];
#pragma unroll
    for (int o_ = 0; o_ < 3; ++o_)
#pragma unroll
      for (int e_ = 0; e_ < 2; ++e_)
        gp[o_][e_] = xb[poff[0][o_][e_]];        // tile 0 (f=0, par=0)
    WSTAGE(LW0, 0);                              // W tile 0
    GISS(1, 0);                                  // slot1 <- tile 1 (f=0, par=1)
#pragma unroll
    for (int o_ = 0; o_ < 3; ++o_){
      unsigned pv_ = (unsigned)f2bf(gp[o_][0]) | ((unsigned)f2bf(gp[o_][1]) << 16);
      *(unsigned*)(lds + LA0 + awr + (o_ << 9)) = pv_;
    }
  }
  BAR();

  // ---------------- phase 1: 64 K-steps, counted vmcnt, LDS-only barriers --------
  // step N: stage W tile N+1, issue gather tile N+2, compute tile N, cvt tile N+1
#pragma unroll 1
  for (int it = 0; it < 16; ++it){
    const int wb = it << 8;
    const int fb = it << 1;
    const bool lastit = (it == 15);
    // j=0 (N=4it): compute (LA0,LW0); stage LW1; issue slot0<-tile N+2; cvt slot1->LA1
    WSTAGE(LW1, wb + 64);
    GISS(0, fb + 1);
    VW(16);
    MM(LA0, LW0);
    CVTWR(1, LA1);
    BAR();
    // j=1: compute (LA1,LW1); stage LW0; issue slot1; cvt slot0->LA0
    WSTAGE(LW0, wb + 128);
    GISS(1, fb + 1);
    VW(16);
    MM(LA1, LW1);
    CVTWR(0, LA0);
    BAR();
    // j=2: compute (LA0,LW0); stage LW1; issue slot0; cvt slot1->LA1
    WSTAGE(LW1, wb + 192);
    if (!lastit){ GISS(0, fb + 2); VW(16); } else { VW(10); }
    MM(LA0, LW0);
    CVTWR(1, LA1);
    BAR();
    // j=3: compute (LA1,LW1); stage LW0; issue slot1; cvt slot0->LA0
    if (!lastit){
      WSTAGE(LW0, wb + 256);
      GISS(1, fb + 2);
      VW(16);
    } else {
      VW(0);
    }
    MM(LA1, LW1);
    if (!lastit) CVTWR(0, LA0);
    BAR();
  }

  // ---------------- epilogue 1: bias + leaky -> A1 bf16 (XOR-swizzled) --------
#pragma unroll
  for (int cn = 0; cn < 4; ++cn){
    const int h  = (w << 6) + (cn << 4) + lr;
#pragma unroll
    for (int fm = 0; fm < 6; ++fm)
#pragma unroll
      for (int r = 0; r < 4; ++r){
        float vv = acc[fm][cn][r] + b1c[cn];
        vv = vv > 0.f ? vv : 0.01f * vv;
        const int row = (fm << 4) + (q << 2) + r;    // D row = 4*(lane>>4)+reg
        int byt = (row << 10) + (h << 1);
        byt ^= (row & 7) << 4;
        *(unsigned short*)(lds + byt) = f2bf(vv);
      }
  }
  BAR();

  // ---------------- phase 2: K=512 vs W2 (direct L2 frags), barrier-free ------
  int w2off[4];
  float b2c[4];
#pragma unroll
  for (int cn = 0; cn < 4; ++cn){
    const int col = (w << 6) + (cn << 4) + lr;
    w2off[cn] = col * 1024 + (q << 4);
    b2c[cn] = b2v[col];
  }
  const char* w2c = (const char*)w2b;
  f32x4 acc2[6][4];
#pragma unroll
  for (int fm = 0; fm < 6; ++fm)
#pragma unroll
    for (int cn = 0; cn < 4; ++cn)
      acc2[fm][cn] = f32x4{0.f, 0.f, 0.f, 0.f};

  bf16x8 c0[4], c1[4];
#pragma unroll
  for (int cn = 0; cn < 4; ++cn) c0[cn] = *(const bf16x8*)(w2c + w2off[cn]);

#pragma unroll 1
  for (int it2 = 0; it2 < 8; ++it2){
    const int s0 = it2 << 1;
#pragma unroll
    for (int cn = 0; cn < 4; ++cn) c1[cn] = *(const bf16x8*)(w2c + w2off[cn] + ((s0 + 1) << 6));
    A2SUB(s0, c0);
    if (it2 < 7){
#pragma unroll
      for (int cn = 0; cn < 4; ++cn) c0[cn] = *(const bf16x8*)(w2c + w2off[cn] + ((s0 + 2) << 6));
    }
    A2SUB(s0 + 1, c1);
  }

  // ---------------- epilogue 2: bias + leaky + mean(o) -> [B,H,T] -------------
#pragma unroll
  for (int cn = 0; cn < 4; ++cn){
    const int h  = (w << 6) + (cn << 4) + lr;
#pragma unroll
    for (int p = 0; p < 2; ++p){
      f32x4 ov;
#pragma unroll
      for (int r = 0; r < 4; ++r){
        float s = 0.f;
#pragma unroll
        for (int oo = 0; oo < 3; ++oo){
          float vv = acc2[oo * 2 + p][cn][r] + b2c[cn];
          vv = vv > 0.f ? vv : 0.01f * vv;
          s += vv;
        }
        ov[r] = s * (1.f / 3.f);
      }
      *(f32x4*)(out + (((long)b * 512 + h) << 8) + t0 + (p << 4) + (q << 2)) = ov;
    }
  }
}

extern "C" void kernel_launch(void* const* d_in, const int* in_sizes, int n_in,
                              void* d_out, int out_size, void* d_ws, size_t ws_size,
                              hipStream_t stream){
  const float* x  = (const float*)d_in[0];
  const float* w1 = (const float*)d_in[1];
  const float* b1 = (const float*)d_in[2];
  const float* w2 = (const float*)d_in[3];
  const float* b2 = (const float*)d_in[4];
  unsigned short* w1b = (unsigned short*)d_ws;            // 512*2048 bf16 = 2 MiB
  unsigned short* w2b = w1b + 512 * 2048;                 // 512*512  bf16 = 0.5 MiB
  conv_w_kernel<<<1280, 256, 0, stream>>>(w1, w2, w1b, w2b);
  fused_kernel<<<256, 512, 0, stream>>>(x, b1, b2, w1b, w2b, (float*)d_out);
}